// Round 15
// baseline (185.912 us; speedup 1.0000x reference)
//
#include <hip/hip_runtime.h>

#define TPB 256
typedef unsigned short us;
typedef __attribute__((ext_vector_type(8))) _Float16 f16x8;
typedef __attribute__((ext_vector_type(2))) _Float16 f16x2;
typedef __attribute__((ext_vector_type(4))) float f32x4;

__device__ inline us f2h(float f){ union{ _Float16 h; us u; } x; x.h = (_Float16)f; return x.u; }
__device__ inline f16x2 u2h2(unsigned u){ union{ unsigned v; f16x2 h; } x; x.v = u; return x.h; }
#define MFMA16(a,b,c) __builtin_amdgcn_mfma_f32_16x16x32_f16((a),(b),(c),0,0,0)

// ---------------------------------------------------------------- x NCHW f32 -> NHWC f16
__global__ __launch_bounds__(256) void k_transpose_x(const float* __restrict__ x,
                                                     us* __restrict__ xT){
  __shared__ float tile[64][65];
  const int y = blockIdx.x, b = blockIdx.y;
  for (int i = threadIdx.x; i < 4096; i += TPB){
    const int c = i >> 6, xx = i & 63;
    tile[c][xx] = x[b*262144 + c*4096 + y*64 + xx];
  }
  __syncthreads();
  for (int i = threadIdx.x; i < 4096; i += TPB){
    const int xx = i >> 6, c = i & 63;
    xT[(size_t)(b*4096 + y*64 + xx)*64 + c] = f2h(tile[c][xx]);
  }
}

// ---------------------------------------------------------------- weights -> fragment-linear f16
// layout: [k(9)][kb][n0][lane(64)][j(8)], elem = W[co=n0*16+(l&15)][c=kb*32+(l>>4)*8+j][k]
__global__ __launch_bounds__(256) void k_prep(
    const float* __restrict__ cw1, const float* __restrict__ ow1, const float* __restrict__ mw1,
    const float* __restrict__ cw2, const float* __restrict__ ow2, const float* __restrict__ mw2,
    us* __restrict__ d1, us* __restrict__ d2, us* __restrict__ a1, us* __restrict__ a2){
  const int e = blockIdx.x*TPB + threadIdx.x;
  if (e < 73728){  // deform1: KB=2, NT=8, per-k 8192
    int k = e/8192, r = e%8192, kb = r/4096, r2 = r%4096;
    int n0 = r2>>9, q = r2&511, l = q>>3, j = q&7;
    int co = n0*16 + (l&15), c = kb*32 + (l>>4)*8 + j;
    d1[e] = f2h(cw1[(co*64 + c)*9 + k]);
  }
  if (e < 147456){ // deform2: KB=4, NT=8, per-k 16384
    int k = e/16384, r = e%16384, kb = r/4096, r2 = r%4096;
    int n0 = r2>>9, q = r2&511, l = q>>3, j = q&7;
    int co = n0*16 + (l&15), c = kb*32 + (l>>4)*8 + j;
    d2[e] = f2h(cw2[(co*128 + c)*9 + k]);
  }
  if (e < 18432){  // aux1: KB=2, NT=2, per-k 2048
    int k = e/2048, r = e%2048, kb = r/1024, r2 = r%1024;
    int n0 = r2>>9, q = r2&511, l = q>>3, j = q&7;
    int co = n0*16 + (l&15), c = kb*32 + (l>>4)*8 + j;
    float w = (co < 18) ? ow1[(co*64 + c)*9 + k] : (co < 27 ? mw1[((co-18)*64 + c)*9 + k] : 0.f);
    a1[e] = f2h(w);
  }
  if (e < 36864){  // aux2: KB=4, NT=2, per-k 4096
    int k = e/4096, r = e%4096, kb = r/1024, r2 = r%1024;
    int n0 = r2>>9, q = r2&511, l = q>>3, j = q&7;
    int co = n0*16 + (l&15), c = kb*32 + (l>>4)*8 + j;
    float w = (co < 18) ? ow2[(co*128 + c)*9 + k] : (co < 27 ? mw2[((co-18)*128 + c)*9 + k] : 0.f);
    a2[e] = f2h(w);
  }
}

// ---------------------------------------------------------------- fused aux + deformable conv (f16, 8 waves)
// One block = one (b,ho), 512 threads. Phase A: cooperative aux conv (unchanged).
// Phase B: BARRIER-FREE. Waves = 4 M-tiles x 2 K-halves. Each lane gathers/blends its
// OWN MFMA A-fragment in registers (px = mt*16+(l&15), ch = kblh*32+(l>>4)*8): no LDS,
// no syncs in the 18-chunk loop; waves drift freely, TLP hides latency. K-halves are
// summed once at the epilogue via LDS.
template<int CIN, int STAGE>
__global__ __launch_bounds__(512, 4) void k_fused(
    const us* __restrict__ inT,
    const us* __restrict__ wb_aux, const us* __restrict__ wb_def,
    const float* __restrict__ bn_g, const float* __restrict__ bn_b,
    const float* __restrict__ bn_m, const float* __restrict__ bn_v,
    us* __restrict__ outT, float* __restrict__ partial){
  constexpr int KB2  = CIN/64;              // 64-ch chunks per tap
  constexpr int NC   = 9*KB2;
  constexpr int WE_A = 2*(CIN/32)*512;
  constexpr int WE_D = 8*(CIN/32)*512;

  __shared__ __align__(16) us pool[12672];  // rows 198*64 | am f32[27*66] | epilogue reduce
  __shared__ uint4 otab[576];               // 4 corner BYTE offsets (pre-multiplied)
  __shared__ uint2 wtab[576];               // f16 (w00,w01),(w10,w11)
  __shared__ float extra[256];

  const int id  = blockIdx.x;
  const int nid = (id & 7)*128 + (id >> 3); // XCD swizzle (1024 % 8 == 0, bijective)
  const int b = nid >> 6, ho = nid & 63;
  const int tid = threadIdx.x;
  const us* __restrict__ inb = inT + (size_t)b*4096*CIN;
  const char* __restrict__ inbc = (const char*)inb;

  if (STAGE == 1 && tid < 128){
    float inv = rsqrtf(bn_v[tid] + 1e-5f)*bn_g[tid];
    extra[tid] = inv; extra[128 + tid] = bn_b[tid] - bn_m[tid]*inv;
  }

  const int lane = tid & 63, lr = lane & 15, lg = lane >> 4;
  const int wv = tid >> 6;                  // 8 waves
  const int mh = wv & 3, nh = wv >> 2;      // phase A roles

  // ===== phase A: aux conv (register-prefetched rows) =====
  f32x4 aacc = (f32x4){0.f,0.f,0.f,0.f};
  auto load_rows = [&](int kb2, uint4* rq){
    #pragma unroll
    for (int it = 0; it < 4; ++it){
      const int s = it*512 + tid;
      if (s < 1584){
        const int slot = s >> 3, cq = s & 7;
        const int r = slot/66, p = slot - r*66;
        const int y = ho - 1 + r, x = p - 1;
        rq[it] = make_uint4(0u,0u,0u,0u);
        if (y >= 0 && y < 64 && x >= 0 && x < 64)
          rq[it] = *(const uint4*)(inb + (size_t)(y*64 + x)*CIN + kb2*64 + cq*8);
      }
    }
  };
  auto write_rows = [&](const uint4* rq){
    #pragma unroll
    for (int it = 0; it < 4; ++it){
      const int s = it*512 + tid;
      if (s < 1584){
        const int slot = s >> 3, cq = s & 7;
        *(uint4*)(pool + slot*64 + ((cq ^ (slot & 7))*8)) = rq[it];
      }
    }
  };
  auto mfma_aux = [&](int kb2){
    #pragma unroll
    for (int k = 0; k < 9; ++k){
      const int kh = k/3, kw = k - kh*3;
      const int slot = kh*66 + mh*16 + lr + kw;
      #pragma unroll
      for (int kbl = 0; kbl < 2; ++kbl){
        f16x8 a = *(const f16x8*)(pool + slot*64 + (((kbl*4 + lg) ^ (slot & 7))*8));
        f16x8 bf = *(const f16x8*)(wb_aux + (size_t)k*WE_A + (size_t)((kb2*2 + kbl)*2 + nh)*512 + lane*8);
        aacc = MFMA16(a, bf, aacc);
      }
    }
  };
  {
    uint4 rqA[4], rqB[4];
    load_rows(0, rqA);
    write_rows(rqA);
    if constexpr (KB2 == 2) load_rows(1, rqB);   // in flight under MFMA(0)
    __syncthreads();
    mfma_aux(0);
    if constexpr (KB2 == 2){
      __syncthreads();
      write_rows(rqB);
      __syncthreads();
      mfma_aux(1);
    }
  }
  __syncthreads();                           // rows dead; am may alias

  float* am = (float*)pool;                  // [27][66]
  {
    const int co = nh*16 + lr;
    if (co < 27){
      #pragma unroll
      for (int i = 0; i < 4; ++i) am[co*66 + mh*16 + lg*4 + i] = aacc[i];
    }
  }
  __syncthreads();

  // ===== bilinear tables =====
  for (int sid = tid; sid < 576; sid += 512){
    const int k = sid >> 6, px = sid & 63;
    const int kh = k/3, kw = k - kh*3;
    float oy = am[(2*k)*66 + px];
    float ox = am[(2*k+1)*66 + px];
    float mv = 1.f/(1.f + expf(-am[(18+k)*66 + px]));
    float py  = (float)(ho - 1 + kh) + oy;
    float pxx = (float)(px - 1 + kw) + ox;
    float fyf = floorf(py), fxf = floorf(pxx);
    int y0 = (int)fyf, x0 = (int)fxf;
    float dy = py - fyf, dx = pxx - fxf;
    bool vy0 = (y0 >= 0) && (y0 < 64), vy1 = (y0 >= -1) && (y0 < 63);
    bool vx0 = (x0 >= 0) && (x0 < 64), vx1 = (x0 >= -1) && (x0 < 63);
    int y0c = min(max(y0,0),63), y1c = min(max(y0+1,0),63);
    int x0c = min(max(x0,0),63), x1c = min(max(x0+1,0),63);
    const unsigned str = CIN*2u;
    otab[sid] = make_uint4((unsigned)(y0c*64 + x0c)*str, (unsigned)(y0c*64 + x1c)*str,
                           (unsigned)(y1c*64 + x0c)*str, (unsigned)(y1c*64 + x1c)*str);
    float w00 = (1.f-dy)*(1.f-dx)*mv*((vy0 && vx0) ? 1.f : 0.f);
    float w01 = (1.f-dy)*dx     *mv*((vy0 && vx1) ? 1.f : 0.f);
    float w10 = dy*(1.f-dx)     *mv*((vy1 && vx0) ? 1.f : 0.f);
    float w11 = dy*dx           *mv*((vy1 && vx1) ? 1.f : 0.f);
    wtab[sid] = make_uint2((unsigned)f2h(w00) | ((unsigned)f2h(w01) << 16),
                           (unsigned)f2h(w10) | ((unsigned)f2h(w11) << 16));
  }
  __syncthreads();                           // tables ready; phase B is barrier-free

  // ===== phase B: barrier-free deform conv =====
  const int mt = wv & 3, kblh = wv >> 2;     // wave roles: M-tile, K-half
  const int pxw = mt*16 + lr;                // this lane's pixel
  const unsigned cofs = (unsigned)((kblh*32 + lg*8)*2);   // byte offset within chunk channels

  f32x4 acc[8];
  #pragma unroll
  for (int n = 0; n < 8; ++n) acc[n] = (f32x4){0.f,0.f,0.f,0.f};

  auto load_corners = [&](int i, f16x8* cr){
    const int k = i/KB2, kb2 = i - (i/KB2)*KB2;
    const uint4 o = otab[k*64 + pxw];
    const unsigned c0 = (unsigned)(kb2*128) + cofs;
    cr[0] = *(const f16x8*)(inbc + o.x + c0);
    cr[1] = *(const f16x8*)(inbc + o.y + c0);
    cr[2] = *(const f16x8*)(inbc + o.z + c0);
    cr[3] = *(const f16x8*)(inbc + o.w + c0);
  };
  auto do_chunk = [&](int i, const f16x8* cr){
    const int k = i/KB2, kb2 = i - (i/KB2)*KB2;
    const int kb = kb2*2 + kblh;
    const uint2 wp = wtab[k*64 + pxw];
    const f16x2 wAB = u2h2(wp.x), wCD = u2h2(wp.y);
    const _Float16 wA = wAB[0], wB = wAB[1], wC = wCD[0], wD = wCD[1];
    const f16x8 va = (f16x8){wA,wA,wA,wA,wA,wA,wA,wA};
    const f16x8 vb = (f16x8){wB,wB,wB,wB,wB,wB,wB,wB};
    const f16x8 vc = (f16x8){wC,wC,wC,wC,wC,wC,wC,wC};
    const f16x8 vd = (f16x8){wD,wD,wD,wD,wD,wD,wD,wD};
    f16x8 a = cr[0]*va + cr[1]*vb;
    a = a + cr[2]*vc + cr[3]*vd;
    const us* bbase = wb_def + (size_t)k*WE_D + (size_t)(kb*8)*512 + lane*8;
    #pragma unroll
    for (int g = 0; g < 2; ++g){
      f16x8 bf0 = *(const f16x8*)(bbase + (g*4 + 0)*512);
      f16x8 bf1 = *(const f16x8*)(bbase + (g*4 + 1)*512);
      f16x8 bf2 = *(const f16x8*)(bbase + (g*4 + 2)*512);
      f16x8 bf3 = *(const f16x8*)(bbase + (g*4 + 3)*512);
      acc[g*4 + 0] = MFMA16(a, bf0, acc[g*4 + 0]);
      acc[g*4 + 1] = MFMA16(a, bf1, acc[g*4 + 1]);
      acc[g*4 + 2] = MFMA16(a, bf2, acc[g*4 + 2]);
      acc[g*4 + 3] = MFMA16(a, bf3, acc[g*4 + 3]);
    }
  };

  {
    f16x8 crA[4], crB[4];
    load_corners(0, crA);
    for (int ii = 0; ii < NC; ii += 2){
      if (ii + 1 < NC) load_corners(ii+1, crB);   // prefetch odd chunk
      do_chunk(ii, crA);
      if (ii + 2 < NC) load_corners(ii+2, crA);   // prefetch next even chunk
      if (ii + 1 < NC) do_chunk(ii+1, crB);
    }
  }

  // ===== epilogue: combine K-halves, store =====
  if (STAGE == 1){
    float* red = (float*)pool;                 // 2 mt x 8 nt x 64 lanes x f32x4 = 16KB
    #pragma unroll
    for (int r = 0; r < 2; ++r){
      __syncthreads();
      if (kblh == 1 && (mt >> 1) == r){
        #pragma unroll
        for (int nt = 0; nt < 8; ++nt)
          *(f32x4*)&red[(((mt & 1)*8 + nt)*64 + lane)*4] = acc[nt];
      }
      __syncthreads();
      if (kblh == 0 && (mt >> 1) == r){
        #pragma unroll
        for (int nt = 0; nt < 8; ++nt){
          f32x4 p = *(const f32x4*)&red[(((mt & 1)*8 + nt)*64 + lane)*4];
          acc[nt] += p;
        }
      }
    }
    if (kblh == 0){
      const size_t rowbase = (size_t)(b*4096 + ho*64)*128;
      #pragma unroll
      for (int nt = 0; nt < 8; ++nt){
        const int co = nt*16 + lr;
        const float inv = extra[co], bia = extra[128 + co];
        #pragma unroll
        for (int i = 0; i < 4; ++i){
          const int px = mt*16 + lg*4 + i;
          outT[rowbase + (size_t)px*128 + co] = f2h(fmaxf(acc[nt][i]*inv + bia, 0.f));
        }
      }
    }
  } else {
    float* red = (float*)pool;                 // 8 waves x 128 co
    __syncthreads();
    #pragma unroll
    for (int nt = 0; nt < 8; ++nt){
      float s = acc[nt][0] + acc[nt][1] + acc[nt][2] + acc[nt][3];
      s += __shfl_xor(s, 16);
      s += __shfl_xor(s, 32);
      if (lane < 16) red[wv*128 + nt*16 + lane] = s;
    }
    __syncthreads();
    if (tid < 128){
      float s = 0.f;
      #pragma unroll
      for (int w8 = 0; w8 < 8; ++w8) s += red[w8*128 + tid];
      partial[(size_t)(b*64 + ho)*128 + tid] = s;
    }
  }
}

// ---------------------------------------------------------------- pool + BN2 fold
__global__ __launch_bounds__(256) void k_pool(
    const float* __restrict__ partial,
    const float* __restrict__ g2, const float* __restrict__ b2,
    const float* __restrict__ m2, const float* __restrict__ v2,
    float* __restrict__ pooled){
  const int t = blockIdx.x*TPB + threadIdx.x;
  if (t >= 2048) return;
  const int b = t >> 7, c = t & 127;
  float s = 0.f;
  for (int h = 0; h < 64; ++h) s += partial[(b*64 + h)*128 + c];
  const float inv = rsqrtf(v2[c] + 1e-5f)*g2[c];
  pooled[t] = s*(1.f/4096.f)*inv + (b2[c] - m2[c]*inv);
}

// ---------------------------------------------------------------- fc
__global__ __launch_bounds__(256) void k_fc(
    const float* __restrict__ pooled, const float* __restrict__ fcw,
    const float* __restrict__ fcb, float* __restrict__ outp){
  const int t = blockIdx.x*TPB + threadIdx.x;
  if (t >= 16000) return;
  const int b = t/1000, n = t - b*1000;
  const float* p = pooled + b*128;
  const float* w = fcw + n*128;
  float s = fcb[n];
  #pragma unroll
  for (int c = 0; c < 128; c += 4){
    const float4 pv = *(const float4*)(p + c);
    const float4 wv = *(const float4*)(w + c);
    s = fmaf(pv.x, wv.x, s); s = fmaf(pv.y, wv.y, s);
    s = fmaf(pv.z, wv.z, s); s = fmaf(pv.w, wv.w, s);
  }
  outp[t] = s;
}

extern "C" void kernel_launch(void* const* d_in, const int* in_sizes, int n_in,
                              void* d_out, int out_size, void* d_ws, size_t ws_size,
                              hipStream_t stream){
  const float* x      = (const float*)d_in[0];
  const float* conv1w = (const float*)d_in[1];
  const float* off1w  = (const float*)d_in[2];
  const float* mod1w  = (const float*)d_in[3];
  const float* bn1g   = (const float*)d_in[4];
  const float* bn1b   = (const float*)d_in[5];
  const float* bn1m   = (const float*)d_in[6];
  const float* bn1v   = (const float*)d_in[7];
  const float* conv2w = (const float*)d_in[8];
  const float* off2w  = (const float*)d_in[9];
  const float* mod2w  = (const float*)d_in[10];
  const float* bn2g   = (const float*)d_in[11];
  const float* bn2b   = (const float*)d_in[12];
  const float* bn2m   = (const float*)d_in[13];
  const float* bn2v   = (const float*)d_in[14];
  const float* fcw    = (const float*)d_in[15];
  const float* fcb    = (const float*)d_in[16];

  char* w = (char*)d_ws;
  us*    xT      = (us*)(w);                      //  8,388,608 B
  us*    out1T   = (us*)(w + 8388608);            // 16,777,216 B
  float* partial = (float*)(w + 25165824);        //    524,288 B
  float* pooled  = (float*)(w + 25690112);        //      8,192 B
  us*    wb_d1   = (us*)(w + 25698304);           //    147,456 B
  us*    wb_d2   = (us*)(w + 25845760);           //    294,912 B
  us*    wb_a1   = (us*)(w + 26140672);           //     36,864 B
  us*    wb_a2   = (us*)(w + 26177536);           //     73,728 B

  k_transpose_x<<<dim3(64,16), TPB, 0, stream>>>(x, xT);
  k_prep<<<576, TPB, 0, stream>>>(conv1w, off1w, mod1w, conv2w, off2w, mod2w,
                                  wb_d1, wb_d2, wb_a1, wb_a2);

  k_fused<64,1><<<1024, 512, 0, stream>>>(
      xT, wb_a1, wb_d1, bn1g, bn1b, bn1m, bn1v, out1T, nullptr);
  k_fused<128,2><<<1024, 512, 0, stream>>>(
      out1T, wb_a2, wb_d2, nullptr, nullptr, nullptr, nullptr, nullptr, partial);

  k_pool<<<8, TPB, 0, stream>>>(partial, bn2g, bn2b, bn2m, bn2v, pooled);
  k_fc<<<63, TPB, 0, stream>>>(pooled, fcw, fcb, (float*)d_out);
}

// Round 16
// 93.328 us; speedup vs baseline: 1.9920x; 1.9920x over previous
//
#include <hip/hip_runtime.h>

#define TPB 256
typedef unsigned short us;
typedef __attribute__((ext_vector_type(8))) _Float16 f16x8;
typedef __attribute__((ext_vector_type(2))) _Float16 f16x2;
typedef __attribute__((ext_vector_type(4))) float f32x4;

__device__ inline us f2h(float f){ union{ _Float16 h; us u; } x; x.h = (_Float16)f; return x.u; }
__device__ inline f16x2 u2h2(unsigned u){ union{ unsigned v; f16x2 h; } x; x.v = u; return x.h; }
#define MFMA16(a,b,c) __builtin_amdgcn_mfma_f32_16x16x32_f16((a),(b),(c),0,0,0)

// ---------------------------------------------------------------- x NCHW f32 -> NHWC f16  (+ fused weight prep)
// Transpose grid = dim3(64,16) = 1024 blocks x 256 thr = 262144 threads.
// Weight prep (fragment-linear f16 tables; largest table 147456 elems) rides along
// on the flat thread index — one guarded pass, saves a kernel launch.
__global__ __launch_bounds__(256) void k_transpose_prep(
    const float* __restrict__ x, us* __restrict__ xT,
    const float* __restrict__ cw1, const float* __restrict__ ow1, const float* __restrict__ mw1,
    const float* __restrict__ cw2, const float* __restrict__ ow2, const float* __restrict__ mw2,
    us* __restrict__ d1, us* __restrict__ d2, us* __restrict__ a1, us* __restrict__ a2){
  __shared__ float tile[64][65];
  const int y = blockIdx.x, b = blockIdx.y;
  for (int i = threadIdx.x; i < 4096; i += TPB){
    const int c = i >> 6, xx = i & 63;
    tile[c][xx] = x[b*262144 + c*4096 + y*64 + xx];
  }
  // ---- weight prep on the flat index (independent of the tile) ----
  const int e = (blockIdx.y*64 + blockIdx.x)*TPB + threadIdx.x;
  if (e < 73728){  // deform1: KB=2, NT=8, per-k 8192
    int k = e/8192, r = e%8192, kb = r/4096, r2 = r%4096;
    int n0 = r2>>9, q = r2&511, l = q>>3, j = q&7;
    int co = n0*16 + (l&15), c = kb*32 + (l>>4)*8 + j;
    d1[e] = f2h(cw1[(co*64 + c)*9 + k]);
  }
  if (e < 147456){ // deform2: KB=4, NT=8, per-k 16384
    int k = e/16384, r = e%16384, kb = r/4096, r2 = r%4096;
    int n0 = r2>>9, q = r2&511, l = q>>3, j = q&7;
    int co = n0*16 + (l&15), c = kb*32 + (l>>4)*8 + j;
    d2[e] = f2h(cw2[(co*128 + c)*9 + k]);
  }
  if (e < 18432){  // aux1: KB=2, NT=2, per-k 2048
    int k = e/2048, r = e%2048, kb = r/1024, r2 = r%1024;
    int n0 = r2>>9, q = r2&511, l = q>>3, j = q&7;
    int co = n0*16 + (l&15), c = kb*32 + (l>>4)*8 + j;
    float w = (co < 18) ? ow1[(co*64 + c)*9 + k] : (co < 27 ? mw1[((co-18)*64 + c)*9 + k] : 0.f);
    a1[e] = f2h(w);
  }
  if (e < 36864){  // aux2: KB=4, NT=2, per-k 4096
    int k = e/4096, r = e%4096, kb = r/1024, r2 = r%1024;
    int n0 = r2>>9, q = r2&511, l = q>>3, j = q&7;
    int co = n0*16 + (l&15), c = kb*32 + (l>>4)*8 + j;
    float w = (co < 18) ? ow2[(co*128 + c)*9 + k] : (co < 27 ? mw2[((co-18)*128 + c)*9 + k] : 0.f);
    a2[e] = f2h(w);
  }
  __syncthreads();
  for (int i = threadIdx.x; i < 4096; i += TPB){
    const int xx = i >> 6, c = i & 63;
    xT[(size_t)(b*4096 + y*64 + xx)*64 + c] = f2h(tile[c][xx]);
  }
}

// ---------------------------------------------------------------- fused aux + deformable conv (f16, 8 waves)
// One block = one (b,ho), 512 threads (round-10 best config, verbatim).
// Phase A: aux 3x3 conv, rows reg-prefetched into LDS, MFMA over 9 taps -> 27 aux ch.
// Tables: bilinear corner byte-offsets + f16-packed mask-folded weights.
// Phase B: 2-deep pipelined (tap,64ch) chunks: corner loads for chunk i+2 issued at i,
// blend(i+1) consumes loads issued a full iteration earlier; double-buffered LDS;
// XOR-swizzled 128B rows (conflict-free); waves partition N (B-fragments read once).
template<int CIN, int STAGE>
__global__ __launch_bounds__(512, 4) void k_fused(
    const us* __restrict__ inT,
    const us* __restrict__ wb_aux, const us* __restrict__ wb_def,
    const float* __restrict__ bn_g, const float* __restrict__ bn_b,
    const float* __restrict__ bn_m, const float* __restrict__ bn_v,
    us* __restrict__ outT, float* __restrict__ partial){
  constexpr int KB2  = CIN/64;              // 64-ch chunks per tap
  constexpr int NC   = 9*KB2;
  constexpr int WE_A = 2*(CIN/32)*512;
  constexpr int WE_D = 8*(CIN/32)*512;

  __shared__ __align__(16) us pool[12672];  // rows 198*64 | am f32[27*66] | g 2*4096
  __shared__ uint4 otab[576];               // 4 corner BYTE offsets (pre-multiplied)
  __shared__ uint2 wtab[576];               // f16 (w00,w01),(w10,w11)
  __shared__ float extra[256];

  const int id  = blockIdx.x;
  const int nid = (id & 7)*128 + (id >> 3); // XCD swizzle (1024 % 8 == 0, bijective)
  const int b = nid >> 6, ho = nid & 63;
  const int tid = threadIdx.x;
  const us* __restrict__ inb = inT + (size_t)b*4096*CIN;
  const char* __restrict__ inbc = (const char*)inb;

  if (STAGE == 1 && tid < 128){
    float inv = rsqrtf(bn_v[tid] + 1e-5f)*bn_g[tid];
    extra[tid] = inv; extra[128 + tid] = bn_b[tid] - bn_m[tid]*inv;
  }

  const int lane = tid & 63, lr = lane & 15, lg = lane >> 4;
  const int wv = tid >> 6;                  // 8 waves
  const int mh = wv & 3, nh = wv >> 2;      // phase A roles

  // ===== phase A: aux conv (register-prefetched rows) =====
  f32x4 aacc = (f32x4){0.f,0.f,0.f,0.f};
  auto load_rows = [&](int kb2, uint4* rq){
    #pragma unroll
    for (int it = 0; it < 4; ++it){
      const int s = it*512 + tid;
      if (s < 1584){
        const int slot = s >> 3, cq = s & 7;
        const int r = slot/66, p = slot - r*66;
        const int y = ho - 1 + r, x = p - 1;
        rq[it] = make_uint4(0u,0u,0u,0u);
        if (y >= 0 && y < 64 && x >= 0 && x < 64)
          rq[it] = *(const uint4*)(inb + (size_t)(y*64 + x)*CIN + kb2*64 + cq*8);
      }
    }
  };
  auto write_rows = [&](const uint4* rq){
    #pragma unroll
    for (int it = 0; it < 4; ++it){
      const int s = it*512 + tid;
      if (s < 1584){
        const int slot = s >> 3, cq = s & 7;
        *(uint4*)(pool + slot*64 + ((cq ^ (slot & 7))*8)) = rq[it];
      }
    }
  };
  auto mfma_aux = [&](int kb2){
    #pragma unroll
    for (int k = 0; k < 9; ++k){
      const int kh = k/3, kw = k - kh*3;
      const int slot = kh*66 + mh*16 + lr + kw;
      #pragma unroll
      for (int kbl = 0; kbl < 2; ++kbl){
        f16x8 a = *(const f16x8*)(pool + slot*64 + (((kbl*4 + lg) ^ (slot & 7))*8));
        f16x8 bf = *(const f16x8*)(wb_aux + (size_t)k*WE_A + (size_t)((kb2*2 + kbl)*2 + nh)*512 + lane*8);
        aacc = MFMA16(a, bf, aacc);
      }
    }
  };
  {
    uint4 rqA[4], rqB[4];
    load_rows(0, rqA);
    write_rows(rqA);
    if constexpr (KB2 == 2) load_rows(1, rqB);   // in flight under MFMA(0)
    __syncthreads();
    mfma_aux(0);
    if constexpr (KB2 == 2){
      __syncthreads();
      write_rows(rqB);
      __syncthreads();
      mfma_aux(1);
    }
  }
  __syncthreads();                           // rows dead; am may alias

  float* am = (float*)pool;                  // [27][66]
  {
    const int co = nh*16 + lr;
    if (co < 27){
      #pragma unroll
      for (int i = 0; i < 4; ++i) am[co*66 + mh*16 + lg*4 + i] = aacc[i];
    }
  }
  __syncthreads();

  // ===== bilinear tables =====
  for (int sid = tid; sid < 576; sid += 512){
    const int k = sid >> 6, px = sid & 63;
    const int kh = k/3, kw = k - kh*3;
    float oy = am[(2*k)*66 + px];
    float ox = am[(2*k+1)*66 + px];
    float mv = 1.f/(1.f + expf(-am[(18+k)*66 + px]));
    float py  = (float)(ho - 1 + kh) + oy;
    float pxx = (float)(px - 1 + kw) + ox;
    float fyf = floorf(py), fxf = floorf(pxx);
    int y0 = (int)fyf, x0 = (int)fxf;
    float dy = py - fyf, dx = pxx - fxf;
    bool vy0 = (y0 >= 0) && (y0 < 64), vy1 = (y0 >= -1) && (y0 < 63);
    bool vx0 = (x0 >= 0) && (x0 < 64), vx1 = (x0 >= -1) && (x0 < 63);
    int y0c = min(max(y0,0),63), y1c = min(max(y0+1,0),63);
    int x0c = min(max(x0,0),63), x1c = min(max(x0+1,0),63);
    const unsigned str = CIN*2u;
    otab[sid] = make_uint4((unsigned)(y0c*64 + x0c)*str, (unsigned)(y0c*64 + x1c)*str,
                           (unsigned)(y1c*64 + x0c)*str, (unsigned)(y1c*64 + x1c)*str);
    float w00 = (1.f-dy)*(1.f-dx)*mv*((vy0 && vx0) ? 1.f : 0.f);
    float w01 = (1.f-dy)*dx     *mv*((vy0 && vx1) ? 1.f : 0.f);
    float w10 = dy*(1.f-dx)     *mv*((vy1 && vx0) ? 1.f : 0.f);
    float w11 = dy*dx           *mv*((vy1 && vx1) ? 1.f : 0.f);
    wtab[sid] = make_uint2((unsigned)f2h(w00) | ((unsigned)f2h(w01) << 16),
                           (unsigned)f2h(w10) | ((unsigned)f2h(w11) << 16));
  }
  __syncthreads();                           // am dead; g buffers may alias

  // ===== phase B: deform conv, 2-deep pipelined chunks =====
  f32x4 acc[4];
  #pragma unroll
  for (int m = 0; m < 4; ++m) acc[m] = (f32x4){0.f,0.f,0.f,0.f};

  const int pxs = tid >> 3, cqs = tid & 7;   // stage-role indices

  auto load_corners = [&](int i, f16x8* cr){
    const int k = i/KB2, kb2 = i - (i/KB2)*KB2;
    const uint4 o = otab[k*64 + pxs];
    const unsigned c0 = (unsigned)(kb2*64 + cqs*8)*2u;
    cr[0] = *(const f16x8*)(inbc + o.x + c0);
    cr[1] = *(const f16x8*)(inbc + o.y + c0);
    cr[2] = *(const f16x8*)(inbc + o.z + c0);
    cr[3] = *(const f16x8*)(inbc + o.w + c0);
  };
  auto load_B = [&](int i, f16x8* bbp){
    const int k = i/KB2, kb2 = i - (i/KB2)*KB2;
    #pragma unroll
    for (int kbl = 0; kbl < 2; ++kbl)
      bbp[kbl] = *(const f16x8*)(wb_def + (size_t)k*WE_D + (size_t)((kb2*2 + kbl)*8 + wv)*512 + lane*8);
  };
  auto blend_write = [&](int i, const f16x8* cr, us* dst){
    const int k = i/KB2;
    const uint2 wp = wtab[k*64 + pxs];
    const f16x2 wAB = u2h2(wp.x), wCD = u2h2(wp.y);
    const _Float16 wA = wAB[0], wB = wAB[1], wC = wCD[0], wD = wCD[1];
    const f16x8 va = (f16x8){wA,wA,wA,wA,wA,wA,wA,wA};
    const f16x8 vb = (f16x8){wB,wB,wB,wB,wB,wB,wB,wB};
    const f16x8 vc = (f16x8){wC,wC,wC,wC,wC,wC,wC,wC};
    const f16x8 vd = (f16x8){wD,wD,wD,wD,wD,wD,wD,wD};
    f16x8 r = cr[0]*va + cr[1]*vb;
    r = r + cr[2]*vc + cr[3]*vd;
    *(f16x8*)(dst + pxs*64 + ((cqs ^ (pxs & 7))*8)) = r;
  };
  auto mfma_def = [&](int i, const us* src, const f16x8* bbp){
    #pragma unroll
    for (int kbl = 0; kbl < 2; ++kbl){
      #pragma unroll
      for (int mt = 0; mt < 4; ++mt){
        const int row = mt*16 + lr;
        f16x8 a = *(const f16x8*)(src + row*64 + (((kbl*4 + lg) ^ (row & 7))*8));
        acc[mt] = MFMA16(a, bbp[kbl], acc[mt]);
      }
    }
  };

  us* g0 = pool;
  us* g1 = pool + 4096;
  f16x8 crA[4], crB[4], bbA[2], bbB[2];
  load_corners(0, crA); load_B(0, bbA);
  load_corners(1, crB); load_B(1, bbB);
  blend_write(0, crA, g0);
  __syncthreads();
  for (int ii = 0; ii < NC; ii += 2){
    // even chunk ii : compute g0/bbA, refill crA/bbA with chunk ii+2
    if (ii + 2 < NC) load_corners(ii+2, crA);
    mfma_def(ii, g0, bbA);
    if (ii + 2 < NC) load_B(ii+2, bbA);
    if (ii + 1 < NC) blend_write(ii+1, crB, g1);
    __syncthreads();
    if (ii + 1 < NC){
      // odd chunk ii+1 : compute g1/bbB, refill crB/bbB with chunk ii+3
      if (ii + 3 < NC) load_corners(ii+3, crB);
      mfma_def(ii+1, g1, bbB);
      if (ii + 3 < NC) load_B(ii+3, bbB);
      if (ii + 2 < NC) blend_write(ii+2, crA, g0);
      __syncthreads();
    }
  }

  // ===== epilogue =====
  if (STAGE == 1){
    const size_t rowbase = (size_t)(b*4096 + ho*64)*128;
    const int co = wv*16 + lr;
    const float inv = extra[co], bia = extra[128 + co];
    #pragma unroll
    for (int mt = 0; mt < 4; ++mt){
      const int pxl = mt*16 + lg*4;
      #pragma unroll
      for (int i = 0; i < 4; ++i){
        float v = acc[mt][i]*inv + bia;
        outT[rowbase + (size_t)(pxl + i)*128 + co] = f2h(fmaxf(v, 0.f));
      }
    }
  } else {
    float s = 0.f;
    #pragma unroll
    for (int mt = 0; mt < 4; ++mt)
      s += acc[mt][0] + acc[mt][1] + acc[mt][2] + acc[mt][3];
    s += __shfl_xor(s, 16);
    s += __shfl_xor(s, 32);
    if (lane < 16) extra[wv*16 + lane] = s;
    __syncthreads();
    if (tid < 128) partial[(size_t)(b*64 + ho)*128 + tid] = extra[tid];
  }
}

// ---------------------------------------------------------------- pool + BN2 fold
__global__ __launch_bounds__(256) void k_pool(
    const float* __restrict__ partial,
    const float* __restrict__ g2, const float* __restrict__ b2,
    const float* __restrict__ m2, const float* __restrict__ v2,
    float* __restrict__ pooled){
  const int t = blockIdx.x*TPB + threadIdx.x;
  if (t >= 2048) return;
  const int b = t >> 7, c = t & 127;
  float s = 0.f;
  for (int h = 0; h < 64; ++h) s += partial[(b*64 + h)*128 + c];
  const float inv = rsqrtf(v2[c] + 1e-5f)*g2[c];
  pooled[t] = s*(1.f/4096.f)*inv + (b2[c] - m2[c]*inv);
}

// ---------------------------------------------------------------- fc
__global__ __launch_bounds__(256) void k_fc(
    const float* __restrict__ pooled, const float* __restrict__ fcw,
    const float* __restrict__ fcb, float* __restrict__ outp){
  const int t = blockIdx.x*TPB + threadIdx.x;
  if (t >= 16000) return;
  const int b = t/1000, n = t - b*1000;
  const float* p = pooled + b*128;
  const float* w = fcw + n*128;
  float s = fcb[n];
  #pragma unroll
  for (int c = 0; c < 128; c += 4){
    const float4 pv = *(const float4*)(p + c);
    const float4 wv = *(const float4*)(w + c);
    s = fmaf(pv.x, wv.x, s); s = fmaf(pv.y, wv.y, s);
    s = fmaf(pv.z, wv.z, s); s = fmaf(pv.w, wv.w, s);
  }
  outp[t] = s;
}

extern "C" void kernel_launch(void* const* d_in, const int* in_sizes, int n_in,
                              void* d_out, int out_size, void* d_ws, size_t ws_size,
                              hipStream_t stream){
  const float* x      = (const float*)d_in[0];
  const float* conv1w = (const float*)d_in[1];
  const float* off1w  = (const float*)d_in[2];
  const float* mod1w  = (const float*)d_in[3];
  const float* bn1g   = (const float*)d_in[4];
  const float* bn1b   = (const float*)d_in[5];
  const float* bn1m   = (const float*)d_in[6];
  const float* bn1v   = (const float*)d_in[7];
  const float* conv2w = (const float*)d_in[8];
  const float* off2w  = (const float*)d_in[9];
  const float* mod2w  = (const float*)d_in[10];
  const float* bn2g   = (const float*)d_in[11];
  const float* bn2b   = (const float*)d_in[12];
  const float* bn2m   = (const float*)d_in[13];
  const float* bn2v   = (const float*)d_in[14];
  const float* fcw    = (const float*)d_in[15];
  const float* fcb    = (const float*)d_in[16];

  char* w = (char*)d_ws;
  us*    xT      = (us*)(w);                      //  8,388,608 B
  us*    out1T   = (us*)(w + 8388608);            // 16,777,216 B
  float* partial = (float*)(w + 25165824);        //    524,288 B
  float* pooled  = (float*)(w + 25690112);        //      8,192 B
  us*    wb_d1   = (us*)(w + 25698304);           //    147,456 B
  us*    wb_d2   = (us*)(w + 25845760);           //    294,912 B
  us*    wb_a1   = (us*)(w + 26140672);           //     36,864 B
  us*    wb_a2   = (us*)(w + 26177536);           //     73,728 B

  k_transpose_prep<<<dim3(64,16), TPB, 0, stream>>>(
      x, xT, conv1w, off1w, mod1w, conv2w, off2w, mod2w,
      wb_d1, wb_d2, wb_a1, wb_a2);

  k_fused<64,1><<<1024, 512, 0, stream>>>(
      xT, wb_a1, wb_d1, bn1g, bn1b, bn1m, bn1v, out1T, nullptr);
  k_fused<128,2><<<1024, 512, 0, stream>>>(
      out1T, wb_a2, wb_d2, nullptr, nullptr, nullptr, nullptr, nullptr, partial);

  k_pool<<<8, TPB, 0, stream>>>(partial, bn2g, bn2b, bn2m, bn2v, pooled);
  k_fc<<<63, TPB, 0, stream>>>(pooled, fcw, fcb, (float*)d_out);
}

// Round 17
// 92.857 us; speedup vs baseline: 2.0021x; 1.0051x over previous
//
#include <hip/hip_runtime.h>

#define TPB 256
typedef unsigned short us;
typedef __attribute__((ext_vector_type(8))) _Float16 f16x8;
typedef __attribute__((ext_vector_type(2))) _Float16 f16x2;
typedef __attribute__((ext_vector_type(4))) float f32x4;

__device__ inline us f2h(float f){ union{ _Float16 h; us u; } x; x.h = (_Float16)f; return x.u; }
__device__ inline f16x2 u2h2(unsigned u){ union{ unsigned v; f16x2 h; } x; x.v = u; return x.h; }
#define MFMA16(a,b,c) __builtin_amdgcn_mfma_f32_16x16x32_f16((a),(b),(c),0,0,0)

// ---------------------------------------------------------------- x NCHW f32 -> NHWC f16  (+ fused weight prep)
__global__ __launch_bounds__(256) void k_transpose_prep(
    const float* __restrict__ x, us* __restrict__ xT,
    const float* __restrict__ cw1, const float* __restrict__ ow1, const float* __restrict__ mw1,
    const float* __restrict__ cw2, const float* __restrict__ ow2, const float* __restrict__ mw2,
    us* __restrict__ d1, us* __restrict__ d2, us* __restrict__ a1, us* __restrict__ a2){
  __shared__ float tile[64][65];
  const int y = blockIdx.x, b = blockIdx.y;
  for (int i = threadIdx.x; i < 4096; i += TPB){
    const int c = i >> 6, xx = i & 63;
    tile[c][xx] = x[b*262144 + c*4096 + y*64 + xx];
  }
  const int e = (blockIdx.y*64 + blockIdx.x)*TPB + threadIdx.x;
  if (e < 73728){  // deform1: KB=2, NT=8, per-k 8192
    int k = e/8192, r = e%8192, kb = r/4096, r2 = r%4096;
    int n0 = r2>>9, q = r2&511, l = q>>3, j = q&7;
    int co = n0*16 + (l&15), c = kb*32 + (l>>4)*8 + j;
    d1[e] = f2h(cw1[(co*64 + c)*9 + k]);
  }
  if (e < 147456){ // deform2: KB=4, NT=8, per-k 16384
    int k = e/16384, r = e%16384, kb = r/4096, r2 = r%4096;
    int n0 = r2>>9, q = r2&511, l = q>>3, j = q&7;
    int co = n0*16 + (l&15), c = kb*32 + (l>>4)*8 + j;
    d2[e] = f2h(cw2[(co*128 + c)*9 + k]);
  }
  if (e < 18432){  // aux1: KB=2, NT=2, per-k 2048
    int k = e/2048, r = e%2048, kb = r/1024, r2 = r%1024;
    int n0 = r2>>9, q = r2&511, l = q>>3, j = q&7;
    int co = n0*16 + (l&15), c = kb*32 + (l>>4)*8 + j;
    float w = (co < 18) ? ow1[(co*64 + c)*9 + k] : (co < 27 ? mw1[((co-18)*64 + c)*9 + k] : 0.f);
    a1[e] = f2h(w);
  }
  if (e < 36864){  // aux2: KB=4, NT=2, per-k 4096
    int k = e/4096, r = e%4096, kb = r/1024, r2 = r%1024;
    int n0 = r2>>9, q = r2&511, l = q>>3, j = q&7;
    int co = n0*16 + (l&15), c = kb*32 + (l>>4)*8 + j;
    float w = (co < 18) ? ow2[(co*128 + c)*9 + k] : (co < 27 ? mw2[((co-18)*128 + c)*9 + k] : 0.f);
    a2[e] = f2h(w);
  }
  __syncthreads();
  for (int i = threadIdx.x; i < 4096; i += TPB){
    const int xx = i >> 6, c = i & 63;
    xT[(size_t)(b*4096 + y*64 + xx)*64 + c] = f2h(tile[c][xx]);
  }
}

// ---------------------------------------------------------------- fused aux + deformable conv (f16, 8 waves)
// One block = one (b,ho), 512 threads. Phase B: PAIR-processed chunks with 4 rotating
// LDS buffers -> ONE barrier per 2 chunks (halves the barrier-convoy count vs r16).
// Corners for (i+2,i+3) issued at pair start (consumed a full 16-MFMA pair later).
template<int CIN, int STAGE>
__global__ __launch_bounds__(512, 4) void k_fused(
    const us* __restrict__ inT,
    const us* __restrict__ wb_aux, const us* __restrict__ wb_def,
    const float* __restrict__ bn_g, const float* __restrict__ bn_b,
    const float* __restrict__ bn_m, const float* __restrict__ bn_v,
    us* __restrict__ outT, float* __restrict__ partial){
  constexpr int KB2  = CIN/64;              // 64-ch chunks per tap
  constexpr int NC   = 9*KB2;
  constexpr int NCP  = NC/2;                // full pairs
  constexpr int WE_A = 2*(CIN/32)*512;
  constexpr int WE_D = 8*(CIN/32)*512;

  __shared__ __align__(16) us pool[16384];  // rows 198*64 (25KB) | am | g 4 x 4096 (32KB)
  __shared__ uint4 otab[576];               // 4 corner BYTE offsets (pre-multiplied)
  __shared__ uint2 wtab[576];               // f16 (w00,w01),(w10,w11)
  __shared__ float extra[256];

  const int id  = blockIdx.x;
  const int nid = (id & 7)*128 + (id >> 3); // XCD swizzle (1024 % 8 == 0, bijective)
  const int b = nid >> 6, ho = nid & 63;
  const int tid = threadIdx.x;
  const us* __restrict__ inb = inT + (size_t)b*4096*CIN;
  const char* __restrict__ inbc = (const char*)inb;

  if (STAGE == 1 && tid < 128){
    float inv = rsqrtf(bn_v[tid] + 1e-5f)*bn_g[tid];
    extra[tid] = inv; extra[128 + tid] = bn_b[tid] - bn_m[tid]*inv;
  }

  const int lane = tid & 63, lr = lane & 15, lg = lane >> 4;
  const int wv = tid >> 6;                  // 8 waves
  const int mh = wv & 3, nh = wv >> 2;      // phase A roles

  // ===== phase A: aux conv (register-prefetched rows) =====
  f32x4 aacc = (f32x4){0.f,0.f,0.f,0.f};
  auto load_rows = [&](int kb2, uint4* rq){
    #pragma unroll
    for (int it = 0; it < 4; ++it){
      const int s = it*512 + tid;
      if (s < 1584){
        const int slot = s >> 3, cq = s & 7;
        const int r = slot/66, p = slot - r*66;
        const int y = ho - 1 + r, x = p - 1;
        rq[it] = make_uint4(0u,0u,0u,0u);
        if (y >= 0 && y < 64 && x >= 0 && x < 64)
          rq[it] = *(const uint4*)(inb + (size_t)(y*64 + x)*CIN + kb2*64 + cq*8);
      }
    }
  };
  auto write_rows = [&](const uint4* rq){
    #pragma unroll
    for (int it = 0; it < 4; ++it){
      const int s = it*512 + tid;
      if (s < 1584){
        const int slot = s >> 3, cq = s & 7;
        *(uint4*)(pool + slot*64 + ((cq ^ (slot & 7))*8)) = rq[it];
      }
    }
  };
  auto mfma_aux = [&](int kb2){
    #pragma unroll
    for (int k = 0; k < 9; ++k){
      const int kh = k/3, kw = k - kh*3;
      const int slot = kh*66 + mh*16 + lr + kw;
      #pragma unroll
      for (int kbl = 0; kbl < 2; ++kbl){
        f16x8 a = *(const f16x8*)(pool + slot*64 + (((kbl*4 + lg) ^ (slot & 7))*8));
        f16x8 bf = *(const f16x8*)(wb_aux + (size_t)k*WE_A + (size_t)((kb2*2 + kbl)*2 + nh)*512 + lane*8);
        aacc = MFMA16(a, bf, aacc);
      }
    }
  };
  {
    uint4 rqA[4], rqB[4];
    load_rows(0, rqA);
    write_rows(rqA);
    if constexpr (KB2 == 2) load_rows(1, rqB);   // in flight under MFMA(0)
    __syncthreads();
    mfma_aux(0);
    if constexpr (KB2 == 2){
      __syncthreads();
      write_rows(rqB);
      __syncthreads();
      mfma_aux(1);
    }
  }
  __syncthreads();                           // rows dead; am may alias

  float* am = (float*)pool;                  // [27][66]
  {
    const int co = nh*16 + lr;
    if (co < 27){
      #pragma unroll
      for (int i = 0; i < 4; ++i) am[co*66 + mh*16 + lg*4 + i] = aacc[i];
    }
  }
  __syncthreads();

  // ===== bilinear tables =====
  for (int sid = tid; sid < 576; sid += 512){
    const int k = sid >> 6, px = sid & 63;
    const int kh = k/3, kw = k - kh*3;
    float oy = am[(2*k)*66 + px];
    float ox = am[(2*k+1)*66 + px];
    float mv = 1.f/(1.f + expf(-am[(18+k)*66 + px]));
    float py  = (float)(ho - 1 + kh) + oy;
    float pxx = (float)(px - 1 + kw) + ox;
    float fyf = floorf(py), fxf = floorf(pxx);
    int y0 = (int)fyf, x0 = (int)fxf;
    float dy = py - fyf, dx = pxx - fxf;
    bool vy0 = (y0 >= 0) && (y0 < 64), vy1 = (y0 >= -1) && (y0 < 63);
    bool vx0 = (x0 >= 0) && (x0 < 64), vx1 = (x0 >= -1) && (x0 < 63);
    int y0c = min(max(y0,0),63), y1c = min(max(y0+1,0),63);
    int x0c = min(max(x0,0),63), x1c = min(max(x0+1,0),63);
    const unsigned str = CIN*2u;
    otab[sid] = make_uint4((unsigned)(y0c*64 + x0c)*str, (unsigned)(y0c*64 + x1c)*str,
                           (unsigned)(y1c*64 + x0c)*str, (unsigned)(y1c*64 + x1c)*str);
    float w00 = (1.f-dy)*(1.f-dx)*mv*((vy0 && vx0) ? 1.f : 0.f);
    float w01 = (1.f-dy)*dx     *mv*((vy0 && vx1) ? 1.f : 0.f);
    float w10 = dy*(1.f-dx)     *mv*((vy1 && vx0) ? 1.f : 0.f);
    float w11 = dy*dx           *mv*((vy1 && vx1) ? 1.f : 0.f);
    wtab[sid] = make_uint2((unsigned)f2h(w00) | ((unsigned)f2h(w01) << 16),
                           (unsigned)f2h(w10) | ((unsigned)f2h(w11) << 16));
  }
  __syncthreads();                           // am dead; g buffers may alias

  // ===== phase B: deform conv, pair-processed chunks (1 barrier / 2 chunks) =====
  f32x4 acc[4];
  #pragma unroll
  for (int m = 0; m < 4; ++m) acc[m] = (f32x4){0.f,0.f,0.f,0.f};

  const int pxs = tid >> 3, cqs = tid & 7;   // stage-role indices

  auto load_corners = [&](int i, f16x8* cr){
    const int k = i/KB2, kb2 = i - (i/KB2)*KB2;
    const uint4 o = otab[k*64 + pxs];
    const unsigned c0 = (unsigned)(kb2*64 + cqs*8)*2u;
    cr[0] = *(const f16x8*)(inbc + o.x + c0);
    cr[1] = *(const f16x8*)(inbc + o.y + c0);
    cr[2] = *(const f16x8*)(inbc + o.z + c0);
    cr[3] = *(const f16x8*)(inbc + o.w + c0);
  };
  auto load_B = [&](int i, f16x8* bbp){
    const int k = i/KB2, kb2 = i - (i/KB2)*KB2;
    #pragma unroll
    for (int kbl = 0; kbl < 2; ++kbl)
      bbp[kbl] = *(const f16x8*)(wb_def + (size_t)k*WE_D + (size_t)((kb2*2 + kbl)*8 + wv)*512 + lane*8);
  };
  auto blend_write = [&](int i, const f16x8* cr, us* dst){
    const int k = i/KB2;
    const uint2 wp = wtab[k*64 + pxs];
    const f16x2 wAB = u2h2(wp.x), wCD = u2h2(wp.y);
    const _Float16 wA = wAB[0], wB = wAB[1], wC = wCD[0], wD = wCD[1];
    const f16x8 va = (f16x8){wA,wA,wA,wA,wA,wA,wA,wA};
    const f16x8 vb = (f16x8){wB,wB,wB,wB,wB,wB,wB,wB};
    const f16x8 vc = (f16x8){wC,wC,wC,wC,wC,wC,wC,wC};
    const f16x8 vd = (f16x8){wD,wD,wD,wD,wD,wD,wD,wD};
    f16x8 r = cr[0]*va + cr[1]*vb;
    r = r + cr[2]*vc + cr[3]*vd;
    *(f16x8*)(dst + pxs*64 + ((cqs ^ (pxs & 7))*8)) = r;
  };
  auto mfma_def = [&](int i, const us* src, const f16x8* bbp){
    #pragma unroll
    for (int kbl = 0; kbl < 2; ++kbl){
      #pragma unroll
      for (int mt = 0; mt < 4; ++mt){
        const int row = mt*16 + lr;
        f16x8 a = *(const f16x8*)(src + row*64 + (((kbl*4 + lg) ^ (row & 7))*8));
        acc[mt] = MFMA16(a, bbp[kbl], acc[mt]);
      }
    }
  };

  us* gA0 = pool;
  us* gA1 = pool + 4096;
  us* gB0 = pool + 8192;
  us* gB1 = pool + 12288;
  f16x8 crA[4], crB[4], bbA[2], bbB[2];
  // prologue: chunks 0,1 -> bank A
  load_corners(0, crA); load_B(0, bbA);
  load_corners(1, crB); load_B(1, bbB);
  blend_write(0, crA, gA0);
  blend_write(1, crB, gA1);
  __syncthreads();
  for (int pp = 0; pp < NCP; ++pp){
    const int i = pp*2;
    us* r0 = (pp & 1) ? gB0 : gA0;
    us* r1 = (pp & 1) ? gB1 : gA1;
    us* w0 = (pp & 1) ? gA0 : gB0;
    us* w1 = (pp & 1) ? gA1 : gB1;
    const bool m2 = (i + 2 < NC);
    const bool m3 = (i + 3 < NC);
    if (m2) load_corners(i+2, crA);          // issue early: consumed after 16 MFMAs
    if (m3) load_corners(i+3, crB);
    mfma_def(i, r0, bbA);
    if (m2) load_B(i+2, bbA);                // refill after consumption
    mfma_def(i+1, r1, bbB);
    if (m3) load_B(i+3, bbB);
    if (m2) blend_write(i+2, crA, w0);
    if (m3) blend_write(i+3, crB, w1);
    __syncthreads();
  }
  if constexpr (NC & 1){                     // tail chunk (stage 1: NC=9)
    mfma_def(NC-1, (NCP & 1) ? gB0 : gA0, bbA);
  }

  // ===== epilogue =====
  if (STAGE == 1){
    const size_t rowbase = (size_t)(b*4096 + ho*64)*128;
    const int co = wv*16 + lr;
    const float inv = extra[co], bia = extra[128 + co];
    #pragma unroll
    for (int mt = 0; mt < 4; ++mt){
      const int pxl = mt*16 + lg*4;
      #pragma unroll
      for (int i = 0; i < 4; ++i){
        float v = acc[mt][i]*inv + bia;
        outT[rowbase + (size_t)(pxl + i)*128 + co] = f2h(fmaxf(v, 0.f));
      }
    }
  } else {
    float s = 0.f;
    #pragma unroll
    for (int mt = 0; mt < 4; ++mt)
      s += acc[mt][0] + acc[mt][1] + acc[mt][2] + acc[mt][3];
    s += __shfl_xor(s, 16);
    s += __shfl_xor(s, 32);
    if (lane < 16) extra[wv*16 + lane] = s;
    __syncthreads();
    if (tid < 128) partial[(size_t)(b*64 + ho)*128 + tid] = extra[tid];
  }
}

// ---------------------------------------------------------------- pool + BN2 fold
__global__ __launch_bounds__(256) void k_pool(
    const float* __restrict__ partial,
    const float* __restrict__ g2, const float* __restrict__ b2,
    const float* __restrict__ m2, const float* __restrict__ v2,
    float* __restrict__ pooled){
  const int t = blockIdx.x*TPB + threadIdx.x;
  if (t >= 2048) return;
  const int b = t >> 7, c = t & 127;
  float s = 0.f;
  for (int h = 0; h < 64; ++h) s += partial[(b*64 + h)*128 + c];
  const float inv = rsqrtf(v2[c] + 1e-5f)*g2[c];
  pooled[t] = s*(1.f/4096.f)*inv + (b2[c] - m2[c]*inv);
}

// ---------------------------------------------------------------- fc
__global__ __launch_bounds__(256) void k_fc(
    const float* __restrict__ pooled, const float* __restrict__ fcw,
    const float* __restrict__ fcb, float* __restrict__ outp){
  const int t = blockIdx.x*TPB + threadIdx.x;
  if (t >= 16000) return;
  const int b = t/1000, n = t - b*1000;
  const float* p = pooled + b*128;
  const float* w = fcw + n*128;
  float s = fcb[n];
  #pragma unroll
  for (int c = 0; c < 128; c += 4){
    const float4 pv = *(const float4*)(p + c);
    const float4 wv = *(const float4*)(w + c);
    s = fmaf(pv.x, wv.x, s); s = fmaf(pv.y, wv.y, s);
    s = fmaf(pv.z, wv.z, s); s = fmaf(pv.w, wv.w, s);
  }
  outp[t] = s;
}

extern "C" void kernel_launch(void* const* d_in, const int* in_sizes, int n_in,
                              void* d_out, int out_size, void* d_ws, size_t ws_size,
                              hipStream_t stream){
  const float* x      = (const float*)d_in[0];
  const float* conv1w = (const float*)d_in[1];
  const float* off1w  = (const float*)d_in[2];
  const float* mod1w  = (const float*)d_in[3];
  const float* bn1g   = (const float*)d_in[4];
  const float* bn1b   = (const float*)d_in[5];
  const float* bn1m   = (const float*)d_in[6];
  const float* bn1v   = (const float*)d_in[7];
  const float* conv2w = (const float*)d_in[8];
  const float* off2w  = (const float*)d_in[9];
  const float* mod2w  = (const float*)d_in[10];
  const float* bn2g   = (const float*)d_in[11];
  const float* bn2b   = (const float*)d_in[12];
  const float* bn2m   = (const float*)d_in[13];
  const float* bn2v   = (const float*)d_in[14];
  const float* fcw    = (const float*)d_in[15];
  const float* fcb    = (const float*)d_in[16];

  char* w = (char*)d_ws;
  us*    xT      = (us*)(w);                      //  8,388,608 B
  us*    out1T   = (us*)(w + 8388608);            // 16,777,216 B
  float* partial = (float*)(w + 25165824);        //    524,288 B
  float* pooled  = (float*)(w + 25690112);        //      8,192 B
  us*    wb_d1   = (us*)(w + 25698304);           //    147,456 B
  us*    wb_d2   = (us*)(w + 25845760);           //    294,912 B
  us*    wb_a1   = (us*)(w + 26140672);           //     36,864 B
  us*    wb_a2   = (us*)(w + 26177536);           //     73,728 B

  k_transpose_prep<<<dim3(64,16), TPB, 0, stream>>>(
      x, xT, conv1w, off1w, mod1w, conv2w, off2w, mod2w,
      wb_d1, wb_d2, wb_a1, wb_a2);

  k_fused<64,1><<<1024, 512, 0, stream>>>(
      xT, wb_a1, wb_d1, bn1g, bn1b, bn1m, bn1v, out1T, nullptr);
  k_fused<128,2><<<1024, 512, 0, stream>>>(
      out1T, wb_a2, wb_d2, nullptr, nullptr, nullptr, nullptr, nullptr, partial);

  k_pool<<<8, TPB, 0, stream>>>(partial, bn2g, bn2b, bn2m, bn2v, pooled);
  k_fc<<<63, TPB, 0, stream>>>(pooled, fcw, fcb, (float*)d_out);
}